// Round 9
// baseline (313.632 us; speedup 1.0000x reference)
//
#include <hip/hip_runtime.h>
#include <math.h>

#define O_  32
#define I_  32
#define K_  13
#define N_  4096
#define IK  (I_ * K_)     // 416 floats per (o) row
#define OIK (O_ * IK)     // 13312 floats per n-slice
#define NB  4             // n's per block
#define NF4 (OIK / 4)     // 3328 float4 cells per n-slice
#define CPO (IK / 4)      // 104 float4 cells per o

typedef float f32x4 __attribute__((ext_vector_type(4)));

// Round 9: per-wave-CONTIGUOUS mask stream.
// Evidence chain: occupancy exonerated (R6), macro footprint exonerated
// (R8), issue rate exonerated (R4 warm = 35 TB/s). The one constant across
// all rounds: each wave-instr read 8 discontiguous 128B segments (stride
// 1664B). Every fast pattern on this chip is 1KB/wave contiguous (fills
// 6.7 TB/s, float4-copy 6.29 TB/s) vs our 2.8 TB/s cold scatter.
// Remap: cell idx = j*256+tid -> wave reads 1KB contiguous per instr.
//  - W shares the n-slice layout, so W4[idx] aligns with mask4[idx]; W
//    hoisted to 13 VGPR-float4s (52 VGPR, R1-proven budget).
//  - g index r4 = idx%104 walked incrementally (+48 mod 104, 2 VALU).
//  - per-cell partial dot -> red[idx] in LDS; reduction phase: thread
//    (o=tid>>3, s=tid&7) sums its 13 cells, then same shfl tree + epilogue.
// Predict: cold stream 77 -> ~30us, headline -> 250-265. Null (~291) =>
// pattern-independent cold-read ceiling => R1 is the roofline, revert.
__global__ __launch_bounds__(256, 4) void plaq_kernel(
    const float* __restrict__ x,      // (I, N)
    const float* __restrict__ W,      // (O, I, K)
    const float* __restrict__ b,      // (O,)
    const float* __restrict__ mask,   // (N, O, I, K)
    const int*   __restrict__ shifts, // (N, K)
    float* __restrict__ out)          // (O, N)
{
    __shared__ __align__(16) float g_lds[NB][IK];   // 6.5 KB
    __shared__ __align__(16) float red[NF4];        // 13 KB partials
    const int n0  = blockIdx.x * NB;
    const int tid = threadIdx.x;

    // Gather g[nl][i*13+k] = x[i*N + shifts[(n0+nl)*13+k]]  (1664 elems).
    for (int idx = tid; idx < NB * IK; idx += 256) {
        int nl = idx / IK;
        int r  = idx - nl * IK;
        int i  = r / K_;
        int k  = r - i * K_;
        int s  = shifts[(n0 + nl) * K_ + k];
        g_lds[nl][r] = x[i * N_ + s];
    }

    // Hoist this thread's 13 W cells (same cell indexing as the mask slice;
    // independent of the gather, in flight across the barrier).
    const f32x4* W4 = (const f32x4*)W;
    f32x4 w13[13];
#pragma unroll
    for (int j = 0; j < 13; ++j) w13[j] = W4[j * 256 + tid];
    const float bo = b[tid >> 3];     // epilogue o = tid>>3 (as before)

    __syncthreads();

    const float scale = (float)((2.0 + 2.0 * M_E) / (M_E - 1.0));
    const int r4_0 = tid - (tid / CPO) * CPO;   // tid % 104 (one magic-div)

    for (int nl = 0; nl < NB; ++nl) {
        const int n = n0 + nl;
        const f32x4* m4 = (const f32x4*)(mask + (size_t)n * OIK);
        const float* g  = &g_lds[nl][0];

        // Hot loop: cell idx = j*256+tid. Wave's 64 lanes -> 1KB contiguous
        // global read. Partial 4-dot goes straight to LDS (no p[] array).
        int r4 = r4_0;
#pragma unroll
        for (int j = 0; j < 13; ++j) {
            f32x4 mv = m4[j * 256 + tid];               // contiguous across lanes
            f32x4 gv = *(const f32x4*)(g + 4 * r4);     // consecutive 16B/lane
            f32x4 wg = w13[j] * gv;
            float p  = fmaf(mv.w, wg.w,
                       fmaf(mv.z, wg.z,
                       fmaf(mv.y, wg.y, mv.x * wg.x)));
            red[j * 256 + tid] = p;
            r4 += 48; if (r4 >= CPO) r4 -= CPO;         // (idx+256) % 104
        }
        __syncthreads();

        // Reduce: o owns cells [104o, 104o+104); 8 threads/o sum 13 each,
        // then the same 8-lane shuffle tree + epilogue as R1.
        {
            const int o = tid >> 3, s = tid & 7;
            const float* c = &red[CPO * o + 13 * s];
            float v = c[0];
#pragma unroll
            for (int q = 1; q < 13; ++q) v += c[q];
            v += __shfl_down(v, 4);
            v += __shfl_down(v, 2);
            v += __shfl_down(v, 1);
            if (s == 0) {
                float y  = v + bo;
                float sg = 1.0f / (1.0f + __expf(-y));
                out[o * N_ + n] = (sg - 0.5f) * scale;
            }
        }
        __syncthreads();   // red reused by next nl
    }
}

extern "C" void kernel_launch(void* const* d_in, const int* in_sizes, int n_in,
                              void* d_out, int out_size, void* d_ws, size_t ws_size,
                              hipStream_t stream) {
    const float* x      = (const float*)d_in[0];
    const float* Wconv  = (const float*)d_in[1];
    const float* bconv  = (const float*)d_in[2];
    const float* mask   = (const float*)d_in[3];
    const int*   shifts = (const int*)d_in[4];
    float* out = (float*)d_out;

    plaq_kernel<<<N_ / NB, 256, 0, stream>>>(x, Wconv, bconv, mask, shifts, out);
}